// Round 14
// baseline (2081.240 us; speedup 1.0000x reference)
//
#include <hip/hip_runtime.h>
#include <cstddef>

// Problem constants (reference: B=8, S=512, E=128, H=512, ENC=128)
#define BB 8
#define SS 512
#define EE 128
#define HH 512
#define ENC 128

// ---------------------------------------------------------------------------
// Bit-exact emulation of XLA CPU's EmitTanh (verified bitwise r6..r13).
// All ops rn, NON-fused. __f*_rn intrinsics block compiler contraction.
// NOTE (r8): packed v_pk_* fp32 is NOT bit-identical on gfx950 — scalar only.
// ---------------------------------------------------------------------------
__device__ __forceinline__ float xla_tanhf(float x) {
    const float cx = fminf(fmaxf(x, -9.0f), 9.0f);
    const float x2 = __fmul_rn(cx, cx);
    float p = -2.76076847742355e-16f;
    p = __fadd_rn(__fmul_rn(p, x2), 2.00018790482477e-13f);
    p = __fadd_rn(__fmul_rn(p, x2), -8.60467152213735e-11f);
    p = __fadd_rn(__fmul_rn(p, x2), 5.12229709037114e-08f);
    p = __fadd_rn(__fmul_rn(p, x2), 1.48572235717979e-05f);
    p = __fadd_rn(__fmul_rn(p, x2), 6.37261928875436e-04f);
    p = __fadd_rn(__fmul_rn(p, x2), 4.89352455891786e-03f);
    const float num = __fmul_rn(cx, p);
    float q = 1.19825839466702e-06f;
    q = __fadd_rn(__fmul_rn(q, x2), 1.18534705686654e-04f);
    q = __fadd_rn(__fmul_rn(q, x2), 2.26843463243900e-03f);
    q = __fadd_rn(__fmul_rn(q, x2), 4.89352518554385e-03f);
    const float r = __fdiv_rn(num, q);
    return (fabsf(x) < 0.0004f) ? x : r;
}

// Map a packed chunk-row m -> global action row:
//   b = m >> chsh (CH = chm1+1), global row = b*SS + i0 + (m & chm1)
__device__ __forceinline__ int arow_map(int m, int chm1, int chsh, int i0) {
    return ((m >> chsh) * SS) + i0 + (m & chm1);
}

// ---------------------------------------------------------------------------
// Tiled GEMM, bitwise-preserving XLA-CPU dot semantics (VERIFIED r6..r13 —
// scalar v_mul/v_add only; r8's packed ops regressed). GEMM2 measured at its
// scalar-VALU floor (~437 us/chunk). K-chain: one accumulator per element,
// k0 tiles ascend, inner k ascends — DO NOT TOUCH the arithmetic.
//
// TRANSP=1 (GEMM2 only): block bx covers B-rows o = d*128+e with
// d in [16*bd,16*bd+16), e in [8*be,8*be+8), bd=bx>>4, be=bx&15
// (any 128 rows are a valid B-tile; load coalescing unchanged — rows were
// already 2KB-strided). Epilogue stores C transposed: C[m][e*128+d], so the
// scan can read contiguous w-rows. Values are bit-identical; only the
// storage address of each independent element changes.
// ---------------------------------------------------------------------------
template <int ACT, int MAPROW, int TRANSP>
__global__ __launch_bounds__(256) void gemm_nt(const float* __restrict__ A,
                                               const float* __restrict__ Bm,
                                               const float* __restrict__ bias,
                                               float* __restrict__ C,
                                               int N, int K,
                                               int chm1, int chsh, int i0) {
    __shared__ float As[16][128];
    __shared__ float Bs[16][128];

    const int tid = threadIdx.x;
    const int tx = tid & 15;   // n-direction (8 cols each)
    const int ty = tid >> 4;   // m-direction (8 rows each)
    const int n0 = blockIdx.x * 128;
    const int m0 = blockIdx.y * 128;
    const int bd = blockIdx.x >> 4;   // TRANSP: d-tile (0..7)
    const int be = blockIdx.x & 15;   // TRANSP: e-tile (0..15)

    const int lr = tid >> 2;          // 0..63 (row within tile)
    const int lc = (tid & 3) << 2;    // 0,4,8,12 (col within K-tile)

    const int ga0 = MAPROW ? arow_map(m0 + lr, chm1, chsh, i0) : (m0 + lr);
    const int ga1 = MAPROW ? arow_map(m0 + lr + 64, chm1, chsh, i0) : (m0 + lr + 64);

    // B-row indices for the two loader rows (identity unless TRANSP)
    const int r0 = lr, r1 = lr + 64;
    const int gb0 = TRANSP ? ((bd * 16 + (r0 >> 3)) * 128 + be * 8 + (r0 & 7))
                           : (n0 + r0);
    const int gb1 = TRANSP ? ((bd * 16 + (r1 >> 3)) * 128 + be * 8 + (r1 & 7))
                           : (n0 + r1);

    float acc[8][8];
#pragma unroll
    for (int i = 0; i < 8; ++i)
#pragma unroll
        for (int j = 0; j < 8; ++j) acc[i][j] = 0.f;

    for (int k0 = 0; k0 < K; k0 += 16) {
        const float4 a0 = *(const float4*)(A + (size_t)ga0 * K + (k0 + lc));
        const float4 a1 = *(const float4*)(A + (size_t)ga1 * K + (k0 + lc));
        const float4 b0 = *(const float4*)(Bm + (size_t)gb0 * K + (k0 + lc));
        const float4 b1 = *(const float4*)(Bm + (size_t)gb1 * K + (k0 + lc));

        __syncthreads();  // previous iteration's compute done before overwrite

        As[lc + 0][lr] = a0.x; As[lc + 1][lr] = a0.y;
        As[lc + 2][lr] = a0.z; As[lc + 3][lr] = a0.w;
        As[lc + 0][lr + 64] = a1.x; As[lc + 1][lr + 64] = a1.y;
        As[lc + 2][lr + 64] = a1.z; As[lc + 3][lr + 64] = a1.w;
        Bs[lc + 0][lr] = b0.x; Bs[lc + 1][lr] = b0.y;
        Bs[lc + 2][lr] = b0.z; Bs[lc + 3][lr] = b0.w;
        Bs[lc + 0][lr + 64] = b1.x; Bs[lc + 1][lr + 64] = b1.y;
        Bs[lc + 2][lr + 64] = b1.z; Bs[lc + 3][lr + 64] = b1.w;

        __syncthreads();

#pragma unroll
        for (int k = 0; k < 16; ++k) {   // ascending k within tile
            const float4 av0 = *(const float4*)&As[k][ty * 8];
            const float4 av1 = *(const float4*)&As[k][ty * 8 + 4];
            const float4 bv0 = *(const float4*)&Bs[k][tx * 8];
            const float4 bv1 = *(const float4*)&Bs[k][tx * 8 + 4];
            const float a[8] = {av0.x, av0.y, av0.z, av0.w, av1.x, av1.y, av1.z, av1.w};
            const float b[8] = {bv0.x, bv0.y, bv0.z, bv0.w, bv1.x, bv1.y, bv1.z, bv1.w};
#pragma unroll
            for (int i = 0; i < 8; ++i)
#pragma unroll
                for (int j = 0; j < 8; ++j)
                    acc[i][j] = __fadd_rn(acc[i][j], __fmul_rn(a[i], b[j]));
        }
    }

    // epilogue: + bias (after full k-chain), optional XLA tanh, store
#pragma unroll
    for (int i = 0; i < 8; ++i) {
        const int m = m0 + ty * 8 + i;
        if (TRANSP) {
            // acc[i][j] is element o = (bd*16+tx)*128 + be*8 + j
            // store transposed at C[m][e*128+d], e=be*8+j, d=bd*16+tx:
            // lanes tx contiguous -> 64B full-line writes
#pragma unroll
            for (int j = 0; j < 8; ++j) {
                const int o = (bd * 16 + tx) * 128 + be * 8 + j;
                const float v = __fadd_rn(acc[i][j], bias[o]);
                C[(size_t)m * N + (size_t)(be * 8 + j) * 128 + bd * 16 + tx] = v;
            }
        } else {
            float v[8];
#pragma unroll
            for (int j = 0; j < 8; ++j) {
                const int n = n0 + tx * 8 + j;
                v[j] = __fadd_rn(acc[i][j], bias[n]);
                if (ACT) v[j] = xla_tanhf(v[j]);
            }
            float4* dst = (float4*)(C + (size_t)m * N + (n0 + tx * 8));
            dst[0] = make_float4(v[0], v[1], v[2], v[3]);
            dst[1] = make_float4(v[4], v[5], v[6], v[7]);
        }
    }
}

// ---------------------------------------------------------------------------
// Sequential attractor scan over transposed Wa (WaT[step][e*128+d]).
// One block per batch, 128 threads, thread e = output coord.
// Thread e's w-row is 128 CONTIGUOUS floats -> 32 float4 loads/step (4x
// fewer VMEM instrs than r13's strided b32). Quarter-grain register
// prefetch (distance 3 quarters, 4 x 8-float4 buffers = 128 VGPRs, fits —
// r13-proven). Ping-pong et (r12-proven) -> ONE barrier/step.
// Chain is op-for-op the verified sequence: ONE accumulator, strictly
// ascending d (quarters 0..3, dq ascending, xyzw ascending), non-fused
// __fmul_rn/__fadd_rn — bitwise contract.
// ---------------------------------------------------------------------------
__global__ __launch_bounds__(128, 1) void scan_kernel(const float* __restrict__ Wa,
                                                      const float* __restrict__ e0,
                                                      float* __restrict__ et_state,
                                                      float* __restrict__ out,
                                                      int i0, int CH) {
    const int b = blockIdx.x;
    const int e = threadIdx.x;  // 0..127

    __shared__ float et[2][128];

    int s = 0;
    if (i0 == 0) {
        const float v = e0[e];
        et[0][e] = v;
        out[(size_t)b * SS * ENC + e] = v;
    } else {
        et[0][e] = et_state[b * 128 + e];
    }
    __syncthreads();

    const int start = (i0 == 0) ? 1 : 0;
    const float* Wb = Wa + (size_t)b * CH * (ENC * ENC);
    const int nq = (CH - start) * 4;   // total quarter-tiles this launch

    float4 w4[4][8];   // 4 quarter buffers x 8 float4 = 128 VGPRs

    // preload quarters 0,1,2 of step `start` (contiguous float4 rows)
    {
        const float4* S4 = (const float4*)(Wb + (size_t)start * (ENC * ENC) + e * ENC);
#pragma unroll
        for (int u = 0; u < 8; ++u) w4[0][u] = S4[u];
#pragma unroll
        for (int u = 0; u < 8; ++u) w4[1][u] = S4[8 + u];
#pragma unroll
        for (int u = 0; u < 8; ++u) w4[2][u] = S4[16 + u];
    }
    asm volatile("" ::: "memory");  // loads pinned before first chain

    for (int ii = start; ii < CH; ++ii) {
        float sum = 0.f;   // ONE accumulator, ascending d across all quarters
#pragma unroll
        for (int q = 0; q < 4; ++q) {
            // issue prefetch for quarter gq+3 into buffer (q+3)&3
            const int pf = (ii - start) * 4 + q + 3;
            if (pf < nq) {
                const float4* src4 =
                    (const float4*)(Wb + (size_t)(start + (pf >> 2)) * (ENC * ENC)
                                    + e * ENC) + (pf & 3) * 8;
#pragma unroll
                for (int u = 0; u < 8; ++u) w4[(q + 3) & 3][u] = src4[u];
            }
            asm volatile("" ::: "memory");
            // consume quarter q: d = 32q .. 32q+31, strictly ascending
#pragma unroll
            for (int dq = 0; dq < 8; ++dq) {
                const float4 t4 = *(const float4*)&et[s][q * 32 + dq * 4];
                const float4 wv = w4[q][dq];
                sum = __fadd_rn(sum, __fmul_rn(t4.x, wv.x));
                sum = __fadd_rn(sum, __fmul_rn(t4.y, wv.y));
                sum = __fadd_rn(sum, __fmul_rn(t4.z, wv.z));
                sum = __fadd_rn(sum, __fmul_rn(t4.w, wv.w));
            }
        }
        const float v = fminf(fmaxf(sum, -5.f), 5.f);  // jnp.clip
        out[((size_t)b * SS + (i0 + ii)) * ENC + e] = v;
        et[s ^ 1][e] = v;   // this step's readers use et[s] — no conflict
        __syncthreads();    // publishes et[s^1]; orders next step's overwrite
        s ^= 1;
    }
    et_state[b * 128 + e] = et[s][e];
}

// ---------------------------------------------------------------------------
extern "C" void kernel_launch(void* const* d_in, const int* in_sizes, int n_in,
                              void* d_out, int out_size, void* d_ws, size_t ws_size,
                              hipStream_t stream) {
    const float* A  = (const float*)d_in[0];  // (B,S,E)   = (8,512,128) fp32
    const float* W1 = (const float*)d_in[1];  // (H,E)     = (512,128)  fp32
    const float* b1 = (const float*)d_in[2];  // (H,)      fp32
    const float* W2 = (const float*)d_in[3];  // (ENC*ENC,H) = (16384,512) fp32
    const float* b2 = (const float*)d_in[4];  // (ENC*ENC,) fp32
    const float* e0 = (const float*)d_in[5];  // (1,ENC)   fp32
    float* out = (float*)d_out;               // (B,S,ENC) fp32

    // Pick the largest chunk CH (steps) whose fp32 workspace fits ws_size.
    // ws layout: [et_state 4KB][hidden_c Mc*512 f32][WaT_c Mc*16384 f32], Mc=8*CH
    int CH = 16;  // minimum (Mc=128, one M-tile); needs ~8.7 MB
    for (int c = 512; c >= 16; c >>= 1) {
        const size_t Mc = (size_t)BB * c;
        const size_t need = 4096 + Mc * HH * sizeof(float) +
                            Mc * (size_t)(ENC * ENC) * sizeof(float);
        if (need <= ws_size) { CH = c; break; }
    }
    const int Mc = BB * CH;
    int chsh = 0;
    while ((1 << chsh) < CH) ++chsh;
    const int chm1 = CH - 1;

    float* et_state = (float*)d_ws;
    float* hidden   = (float*)((char*)d_ws + 4096);
    float* Wa       = hidden + (size_t)Mc * HH;   // transposed layout (WaT)

    for (int i0 = 0; i0 < SS; i0 += CH) {
        // GEMM1: hidden_c = tanh(A[chunk rows] @ W1^T + b1)  [Mc x 512, K=128]
        dim3 g1(HH / 128, Mc / 128);
        gemm_nt<1, 1, 0><<<g1, 256, 0, stream>>>(A, W1, b1, hidden, HH, EE,
                                                 chm1, chsh, i0);
        // GEMM2: WaT_c = (hidden_c @ W2^T + b2) stored transposed
        dim3 g2((ENC * ENC) / 128, Mc / 128);
        gemm_nt<0, 0, 1><<<g2, 256, 0, stream>>>(hidden, W2, b2, Wa, ENC * ENC,
                                                 HH, 0, 0, 0);
        // scan this chunk (one workgroup per batch; fp32 state in ws)
        scan_kernel<<<BB, 128, 0, stream>>>(Wa, e0, et_state, out, i0, CH);
    }
}

// Round 15
// 1674.631 us; speedup vs baseline: 1.2428x; 1.2428x over previous
//
#include <hip/hip_runtime.h>
#include <cstddef>

// Problem constants (reference: B=8, S=512, E=128, H=512, ENC=128)
#define BB 8
#define SS 512
#define EE 128
#define HH 512
#define ENC 128

// ---------------------------------------------------------------------------
// Bit-exact emulation of XLA CPU's EmitTanh (verified bitwise r6..r14).
// All ops rn, NON-fused. __f*_rn intrinsics block compiler contraction.
// NOTE (r8): packed v_pk_* fp32 is NOT bit-identical on gfx950 — scalar only.
// ---------------------------------------------------------------------------
__device__ __forceinline__ float xla_tanhf(float x) {
    const float cx = fminf(fmaxf(x, -9.0f), 9.0f);
    const float x2 = __fmul_rn(cx, cx);
    float p = -2.76076847742355e-16f;
    p = __fadd_rn(__fmul_rn(p, x2), 2.00018790482477e-13f);
    p = __fadd_rn(__fmul_rn(p, x2), -8.60467152213735e-11f);
    p = __fadd_rn(__fmul_rn(p, x2), 5.12229709037114e-08f);
    p = __fadd_rn(__fmul_rn(p, x2), 1.48572235717979e-05f);
    p = __fadd_rn(__fmul_rn(p, x2), 6.37261928875436e-04f);
    p = __fadd_rn(__fmul_rn(p, x2), 4.89352455891786e-03f);
    const float num = __fmul_rn(cx, p);
    float q = 1.19825839466702e-06f;
    q = __fadd_rn(__fmul_rn(q, x2), 1.18534705686654e-04f);
    q = __fadd_rn(__fmul_rn(q, x2), 2.26843463243900e-03f);
    q = __fadd_rn(__fmul_rn(q, x2), 4.89352518554385e-03f);
    const float r = __fdiv_rn(num, q);
    return (fabsf(x) < 0.0004f) ? x : r;
}

// Map a packed chunk-row m -> global action row:
//   b = m >> chsh (CH = chm1+1), global row = b*SS + i0 + (m & chm1)
__device__ __forceinline__ int arow_map(int m, int chm1, int chsh, int i0) {
    return ((m >> chsh) * SS) + i0 + (m & chm1);
}

// ---------------------------------------------------------------------------
// Tiled GEMM, bitwise-preserving XLA-CPU dot semantics (VERIFIED r6..r14 —
// scalar v_mul/v_add only; r8's packed ops regressed). GEMM2 measured at its
// scalar-VALU floor (~437 us/chunk). K-chain: one accumulator per element,
// k0 tiles ascend, inner k ascends — DO NOT TOUCH the arithmetic.
//
// TRANSP=1 (GEMM2 only): block bx covers B-rows o = d*128+e with
// d in [16*bd,16*bd+16), e in [8*be,8*be+8)  (bd=bx>>4, be=bx&15).
// Epilogue stores the d-INTERLEAVED layout:
//   Wa4[m][(d>>2)*128 + e] as float4, component (d&3)  <=>
//   C[m*N + ((d>>2)*128+e)*4 + (d&3)]
// so the scan's per-thread quarter loads become lane-consecutive float4
// (1 KB contiguous per wave-instruction — 16 full lines, fixes r14's
// 64-lines-per-instr scatter). Values bit-identical; only addresses change.
// ---------------------------------------------------------------------------
template <int ACT, int MAPROW, int TRANSP>
__global__ __launch_bounds__(256) void gemm_nt(const float* __restrict__ A,
                                               const float* __restrict__ Bm,
                                               const float* __restrict__ bias,
                                               float* __restrict__ C,
                                               int N, int K,
                                               int chm1, int chsh, int i0) {
    __shared__ float As[16][128];
    __shared__ float Bs[16][128];

    const int tid = threadIdx.x;
    const int tx = tid & 15;   // n-direction (8 cols each)
    const int ty = tid >> 4;   // m-direction (8 rows each)
    const int n0 = blockIdx.x * 128;
    const int m0 = blockIdx.y * 128;
    const int bd = blockIdx.x >> 4;   // TRANSP: d-tile (0..7)
    const int be = blockIdx.x & 15;   // TRANSP: e-tile (0..15)

    const int lr = tid >> 2;          // 0..63 (row within tile)
    const int lc = (tid & 3) << 2;    // 0,4,8,12 (col within K-tile)

    const int ga0 = MAPROW ? arow_map(m0 + lr, chm1, chsh, i0) : (m0 + lr);
    const int ga1 = MAPROW ? arow_map(m0 + lr + 64, chm1, chsh, i0) : (m0 + lr + 64);

    // B-row indices for the two loader rows (identity unless TRANSP)
    const int r0 = lr, r1 = lr + 64;
    const int gb0 = TRANSP ? ((bd * 16 + (r0 >> 3)) * 128 + be * 8 + (r0 & 7))
                           : (n0 + r0);
    const int gb1 = TRANSP ? ((bd * 16 + (r1 >> 3)) * 128 + be * 8 + (r1 & 7))
                           : (n0 + r1);

    float acc[8][8];
#pragma unroll
    for (int i = 0; i < 8; ++i)
#pragma unroll
        for (int j = 0; j < 8; ++j) acc[i][j] = 0.f;

    for (int k0 = 0; k0 < K; k0 += 16) {
        const float4 a0 = *(const float4*)(A + (size_t)ga0 * K + (k0 + lc));
        const float4 a1 = *(const float4*)(A + (size_t)ga1 * K + (k0 + lc));
        const float4 b0 = *(const float4*)(Bm + (size_t)gb0 * K + (k0 + lc));
        const float4 b1 = *(const float4*)(Bm + (size_t)gb1 * K + (k0 + lc));

        __syncthreads();  // previous iteration's compute done before overwrite

        As[lc + 0][lr] = a0.x; As[lc + 1][lr] = a0.y;
        As[lc + 2][lr] = a0.z; As[lc + 3][lr] = a0.w;
        As[lc + 0][lr + 64] = a1.x; As[lc + 1][lr + 64] = a1.y;
        As[lc + 2][lr + 64] = a1.z; As[lc + 3][lr + 64] = a1.w;
        Bs[lc + 0][lr] = b0.x; Bs[lc + 1][lr] = b0.y;
        Bs[lc + 2][lr] = b0.z; Bs[lc + 3][lr] = b0.w;
        Bs[lc + 0][lr + 64] = b1.x; Bs[lc + 1][lr + 64] = b1.y;
        Bs[lc + 2][lr + 64] = b1.z; Bs[lc + 3][lr + 64] = b1.w;

        __syncthreads();

#pragma unroll
        for (int k = 0; k < 16; ++k) {   // ascending k within tile
            const float4 av0 = *(const float4*)&As[k][ty * 8];
            const float4 av1 = *(const float4*)&As[k][ty * 8 + 4];
            const float4 bv0 = *(const float4*)&Bs[k][tx * 8];
            const float4 bv1 = *(const float4*)&Bs[k][tx * 8 + 4];
            const float a[8] = {av0.x, av0.y, av0.z, av0.w, av1.x, av1.y, av1.z, av1.w};
            const float b[8] = {bv0.x, bv0.y, bv0.z, bv0.w, bv1.x, bv1.y, bv1.z, bv1.w};
#pragma unroll
            for (int i = 0; i < 8; ++i)
#pragma unroll
                for (int j = 0; j < 8; ++j)
                    acc[i][j] = __fadd_rn(acc[i][j], __fmul_rn(a[i], b[j]));
        }
    }

    // epilogue: + bias (after full k-chain), optional XLA tanh, store
#pragma unroll
    for (int i = 0; i < 8; ++i) {
        const int m = m0 + ty * 8 + i;
        if (TRANSP) {
            // acc[i][j] is element o = d*128 + e, d = bd*16+tx, e = be*8+j.
            // d-interleaved store: C[m][((d>>2)*128 + e)*4 + (d&3)]
            const int d = bd * 16 + tx;
#pragma unroll
            for (int j = 0; j < 8; ++j) {
                const int ee = be * 8 + j;
                const int o = d * 128 + ee;
                const float v = __fadd_rn(acc[i][j], bias[o]);
                C[(size_t)m * N + ((size_t)(d >> 2) * 128 + ee) * 4 + (d & 3)] = v;
            }
        } else {
            float v[8];
#pragma unroll
            for (int j = 0; j < 8; ++j) {
                const int n = n0 + tx * 8 + j;
                v[j] = __fadd_rn(acc[i][j], bias[n]);
                if (ACT) v[j] = xla_tanhf(v[j]);
            }
            float4* dst = (float4*)(C + (size_t)m * N + (n0 + tx * 8));
            dst[0] = make_float4(v[0], v[1], v[2], v[3]);
            dst[1] = make_float4(v[4], v[5], v[6], v[7]);
        }
    }
}

// ---------------------------------------------------------------------------
// Sequential attractor scan over d-interleaved Wa4.
// One block per batch, 128 threads (2 waves), thread e = output coord.
// Wa4[step][(d>>2)*128 + e] (float4 holds W[d..d+3][e]): thread e's quarter
// = 8 float4 at lane-consecutive addresses -> 1 KB contiguous per
// wave-instruction, 16 full lines (fixes r14's scatter AND r13's
// 256 B/instr MLP cap: ~24 outstanding dwordx4 = 24 KB in flight/wave,
// covers HBM latency).
// Quarter-grain register pipeline, distance 3 (4 x 8 float4 = 128 VGPRs,
// r13-proven); ping-pong et, ONE barrier/step (r14-proven).
// Chain is op-for-op the verified sequence: ONE accumulator, strictly
// ascending d (q asc, dq asc, x,y,z,w = d,d+1,d+2,d+3), non-fused
// __fmul_rn/__fadd_rn — bitwise contract.
// ---------------------------------------------------------------------------
__global__ __launch_bounds__(128, 1) void scan_kernel(const float* __restrict__ Wa,
                                                      const float* __restrict__ e0,
                                                      float* __restrict__ et_state,
                                                      float* __restrict__ out,
                                                      int i0, int CH) {
    const int b = blockIdx.x;
    const int e = threadIdx.x;  // 0..127

    __shared__ float et[2][128];

    int s = 0;
    if (i0 == 0) {
        const float v = e0[e];
        et[0][e] = v;
        out[(size_t)b * SS * ENC + e] = v;
    } else {
        et[0][e] = et_state[b * 128 + e];
    }
    __syncthreads();

    const int start = (i0 == 0) ? 1 : 0;
    const float4* Wb4 = (const float4*)(Wa + (size_t)b * CH * (ENC * ENC));
    const int nq = (CH - start) * 4;   // total quarter-tiles this launch
    // step stride in float4 units: ENC*ENC/4 = 4096; quarter stride: 8*128

    float4 w4[4][8];   // 4 quarter buffers x 8 float4 = 128 VGPRs

    // preload quarters 0,1,2 of step `start`
    {
        const float4* S4 = Wb4 + (size_t)start * 4096 + e;
#pragma unroll
        for (int u = 0; u < 8; ++u) w4[0][u] = S4[u * 128];
#pragma unroll
        for (int u = 0; u < 8; ++u) w4[1][u] = S4[(8 + u) * 128];
#pragma unroll
        for (int u = 0; u < 8; ++u) w4[2][u] = S4[(16 + u) * 128];
    }
    asm volatile("" ::: "memory");  // loads pinned before first chain

    for (int ii = start; ii < CH; ++ii) {
        float sum = 0.f;   // ONE accumulator, ascending d across all quarters
#pragma unroll
        for (int q = 0; q < 4; ++q) {
            // issue prefetch for quarter gq+3 into buffer (q+3)&3
            const int pf = (ii - start) * 4 + q + 3;
            if (pf < nq) {
                const float4* P4 = Wb4 + (size_t)(start + (pf >> 2)) * 4096
                                       + (size_t)(pf & 3) * 8 * 128 + e;
#pragma unroll
                for (int u = 0; u < 8; ++u) w4[(q + 3) & 3][u] = P4[u * 128];
            }
            asm volatile("" ::: "memory");
            // consume quarter q: d = 32q .. 32q+31, strictly ascending
#pragma unroll
            for (int dq = 0; dq < 8; ++dq) {
                const float4 t4 = *(const float4*)&et[s][q * 32 + dq * 4];
                const float4 wv = w4[q][dq];   // W[d..d+3][e], d = 32q+4dq
                sum = __fadd_rn(sum, __fmul_rn(t4.x, wv.x));
                sum = __fadd_rn(sum, __fmul_rn(t4.y, wv.y));
                sum = __fadd_rn(sum, __fmul_rn(t4.z, wv.z));
                sum = __fadd_rn(sum, __fmul_rn(t4.w, wv.w));
            }
        }
        const float v = fminf(fmaxf(sum, -5.f), 5.f);  // jnp.clip
        out[((size_t)b * SS + (i0 + ii)) * ENC + e] = v;
        et[s ^ 1][e] = v;   // this step's readers use et[s] — no conflict
        __syncthreads();    // publishes et[s^1]; orders next step's overwrite
        s ^= 1;
    }
    et_state[b * 128 + e] = et[s][e];
}

// ---------------------------------------------------------------------------
extern "C" void kernel_launch(void* const* d_in, const int* in_sizes, int n_in,
                              void* d_out, int out_size, void* d_ws, size_t ws_size,
                              hipStream_t stream) {
    const float* A  = (const float*)d_in[0];  // (B,S,E)   = (8,512,128) fp32
    const float* W1 = (const float*)d_in[1];  // (H,E)     = (512,128)  fp32
    const float* b1 = (const float*)d_in[2];  // (H,)      fp32
    const float* W2 = (const float*)d_in[3];  // (ENC*ENC,H) = (16384,512) fp32
    const float* b2 = (const float*)d_in[4];  // (ENC*ENC,) fp32
    const float* e0 = (const float*)d_in[5];  // (1,ENC)   fp32
    float* out = (float*)d_out;               // (B,S,ENC) fp32

    // Pick the largest chunk CH (steps) whose fp32 workspace fits ws_size.
    // ws layout: [et_state 4KB][hidden_c Mc*512 f32][Wa4_c Mc*16384 f32], Mc=8*CH
    int CH = 16;  // minimum (Mc=128, one M-tile); needs ~8.7 MB
    for (int c = 512; c >= 16; c >>= 1) {
        const size_t Mc = (size_t)BB * c;
        const size_t need = 4096 + Mc * HH * sizeof(float) +
                            Mc * (size_t)(ENC * ENC) * sizeof(float);
        if (need <= ws_size) { CH = c; break; }
    }
    const int Mc = BB * CH;
    int chsh = 0;
    while ((1 << chsh) < CH) ++chsh;
    const int chm1 = CH - 1;

    float* et_state = (float*)d_ws;
    float* hidden   = (float*)((char*)d_ws + 4096);
    float* Wa       = hidden + (size_t)Mc * HH;   // d-interleaved layout (Wa4)

    for (int i0 = 0; i0 < SS; i0 += CH) {
        // GEMM1: hidden_c = tanh(A[chunk rows] @ W1^T + b1)  [Mc x 512, K=128]
        dim3 g1(HH / 128, Mc / 128);
        gemm_nt<1, 1, 0><<<g1, 256, 0, stream>>>(A, W1, b1, hidden, HH, EE,
                                                 chm1, chsh, i0);
        // GEMM2: Wa4_c = (hidden_c @ W2^T + b2) stored d-interleaved
        dim3 g2((ENC * ENC) / 128, Mc / 128);
        gemm_nt<0, 0, 1><<<g2, 256, 0, stream>>>(hidden, W2, b2, Wa, ENC * ENC,
                                                 HH, 0, 0, 0);
        // scan this chunk (one workgroup per batch; fp32 state in ws)
        scan_kernel<<<BB, 128, 0, stream>>>(Wa, e0, et_state, out, i0, CH);
    }
}

// Round 16
// 1424.968 us; speedup vs baseline: 1.4606x; 1.1752x over previous
//
#include <hip/hip_runtime.h>
#include <cstddef>

// Problem constants (reference: B=8, S=512, E=128, H=512, ENC=128)
#define BB 8
#define SS 512
#define EE 128
#define HH 512
#define ENC 128

// ---------------------------------------------------------------------------
// Bit-exact emulation of XLA CPU's EmitTanh (verified bitwise r6..r15).
// All ops rn, NON-fused. __f*_rn intrinsics block compiler contraction.
// NOTE (r8): packed v_pk_* fp32 is NOT bit-identical on gfx950 — scalar only.
// ---------------------------------------------------------------------------
__device__ __forceinline__ float xla_tanhf(float x) {
    const float cx = fminf(fmaxf(x, -9.0f), 9.0f);
    const float x2 = __fmul_rn(cx, cx);
    float p = -2.76076847742355e-16f;
    p = __fadd_rn(__fmul_rn(p, x2), 2.00018790482477e-13f);
    p = __fadd_rn(__fmul_rn(p, x2), -8.60467152213735e-11f);
    p = __fadd_rn(__fmul_rn(p, x2), 5.12229709037114e-08f);
    p = __fadd_rn(__fmul_rn(p, x2), 1.48572235717979e-05f);
    p = __fadd_rn(__fmul_rn(p, x2), 6.37261928875436e-04f);
    p = __fadd_rn(__fmul_rn(p, x2), 4.89352455891786e-03f);
    const float num = __fmul_rn(cx, p);
    float q = 1.19825839466702e-06f;
    q = __fadd_rn(__fmul_rn(q, x2), 1.18534705686654e-04f);
    q = __fadd_rn(__fmul_rn(q, x2), 2.26843463243900e-03f);
    q = __fadd_rn(__fmul_rn(q, x2), 4.89352518554385e-03f);
    const float r = __fdiv_rn(num, q);
    return (fabsf(x) < 0.0004f) ? x : r;
}

// Map a packed chunk-row m -> global action row:
//   b = m >> chsh (CH = chm1+1), global row = b*SS + i0 + (m & chm1)
__device__ __forceinline__ int arow_map(int m, int chm1, int chsh, int i0) {
    return ((m >> chsh) * SS) + i0 + (m & chm1);
}

// ---------------------------------------------------------------------------
// Tiled GEMM, bitwise-preserving XLA-CPU dot semantics (VERIFIED r6..r15 —
// scalar v_mul/v_add only; r8's packed ops regressed). GEMM2 measured at its
// scalar-VALU floor (~437 us/chunk, VALUBusy 64%). K-chain: one accumulator
// per element, k0 tiles ascend, inner k ascends — DO NOT TOUCH.
//
// TRANSP=1 (GEMM2 only): block bx covers B-rows o = d*128+e with
// d in [16*bd,16*bd+16), e in [8*be,8*be+8)  (bd=bx>>4, be=bx&15).
// Epilogue stores the d-INTERLEAVED layout:
//   Wa4[m][(d>>2)*128 + e] as float4 component (d&3)
// so the scan's quarter loads are lane-consecutive float4 (1 KB contiguous
// per wave-instruction — r15-proven). Values bit-identical; address-only.
// ---------------------------------------------------------------------------
template <int ACT, int MAPROW, int TRANSP>
__global__ __launch_bounds__(256) void gemm_nt(const float* __restrict__ A,
                                               const float* __restrict__ Bm,
                                               const float* __restrict__ bias,
                                               float* __restrict__ C,
                                               int N, int K,
                                               int chm1, int chsh, int i0) {
    __shared__ float As[16][128];
    __shared__ float Bs[16][128];

    const int tid = threadIdx.x;
    const int tx = tid & 15;   // n-direction (8 cols each)
    const int ty = tid >> 4;   // m-direction (8 rows each)
    const int n0 = blockIdx.x * 128;
    const int m0 = blockIdx.y * 128;
    const int bd = blockIdx.x >> 4;   // TRANSP: d-tile (0..7)
    const int be = blockIdx.x & 15;   // TRANSP: e-tile (0..15)

    const int lr = tid >> 2;          // 0..63 (row within tile)
    const int lc = (tid & 3) << 2;    // 0,4,8,12 (col within K-tile)

    const int ga0 = MAPROW ? arow_map(m0 + lr, chm1, chsh, i0) : (m0 + lr);
    const int ga1 = MAPROW ? arow_map(m0 + lr + 64, chm1, chsh, i0) : (m0 + lr + 64);

    // B-row indices for the two loader rows (identity unless TRANSP)
    const int r0 = lr, r1 = lr + 64;
    const int gb0 = TRANSP ? ((bd * 16 + (r0 >> 3)) * 128 + be * 8 + (r0 & 7))
                           : (n0 + r0);
    const int gb1 = TRANSP ? ((bd * 16 + (r1 >> 3)) * 128 + be * 8 + (r1 & 7))
                           : (n0 + r1);

    float acc[8][8];
#pragma unroll
    for (int i = 0; i < 8; ++i)
#pragma unroll
        for (int j = 0; j < 8; ++j) acc[i][j] = 0.f;

    for (int k0 = 0; k0 < K; k0 += 16) {
        const float4 a0 = *(const float4*)(A + (size_t)ga0 * K + (k0 + lc));
        const float4 a1 = *(const float4*)(A + (size_t)ga1 * K + (k0 + lc));
        const float4 b0 = *(const float4*)(Bm + (size_t)gb0 * K + (k0 + lc));
        const float4 b1 = *(const float4*)(Bm + (size_t)gb1 * K + (k0 + lc));

        __syncthreads();  // previous iteration's compute done before overwrite

        As[lc + 0][lr] = a0.x; As[lc + 1][lr] = a0.y;
        As[lc + 2][lr] = a0.z; As[lc + 3][lr] = a0.w;
        As[lc + 0][lr + 64] = a1.x; As[lc + 1][lr + 64] = a1.y;
        As[lc + 2][lr + 64] = a1.z; As[lc + 3][lr + 64] = a1.w;
        Bs[lc + 0][lr] = b0.x; Bs[lc + 1][lr] = b0.y;
        Bs[lc + 2][lr] = b0.z; Bs[lc + 3][lr] = b0.w;
        Bs[lc + 0][lr + 64] = b1.x; Bs[lc + 1][lr + 64] = b1.y;
        Bs[lc + 2][lr + 64] = b1.z; Bs[lc + 3][lr + 64] = b1.w;

        __syncthreads();

#pragma unroll
        for (int k = 0; k < 16; ++k) {   // ascending k within tile
            const float4 av0 = *(const float4*)&As[k][ty * 8];
            const float4 av1 = *(const float4*)&As[k][ty * 8 + 4];
            const float4 bv0 = *(const float4*)&Bs[k][tx * 8];
            const float4 bv1 = *(const float4*)&Bs[k][tx * 8 + 4];
            const float a[8] = {av0.x, av0.y, av0.z, av0.w, av1.x, av1.y, av1.z, av1.w};
            const float b[8] = {bv0.x, bv0.y, bv0.z, bv0.w, bv1.x, bv1.y, bv1.z, bv1.w};
#pragma unroll
            for (int i = 0; i < 8; ++i)
#pragma unroll
                for (int j = 0; j < 8; ++j)
                    acc[i][j] = __fadd_rn(acc[i][j], __fmul_rn(a[i], b[j]));
        }
    }

    // epilogue: + bias (after full k-chain), optional XLA tanh, store
#pragma unroll
    for (int i = 0; i < 8; ++i) {
        const int m = m0 + ty * 8 + i;
        if (TRANSP) {
            // acc[i][j] is element o = d*128 + e, d = bd*16+tx, e = be*8+j.
            // d-interleaved store: C[m][((d>>2)*128 + e)*4 + (d&3)]
            const int d = bd * 16 + tx;
#pragma unroll
            for (int j = 0; j < 8; ++j) {
                const int ee = be * 8 + j;
                const int o = d * 128 + ee;
                const float v = __fadd_rn(acc[i][j], bias[o]);
                C[(size_t)m * N + ((size_t)(d >> 2) * 128 + ee) * 4 + (d & 3)] = v;
            }
        } else {
            float v[8];
#pragma unroll
            for (int j = 0; j < 8; ++j) {
                const int n = n0 + tx * 8 + j;
                v[j] = __fadd_rn(acc[i][j], bias[n]);
                if (ACT) v[j] = xla_tanhf(v[j]);
            }
            float4* dst = (float4*)(C + (size_t)m * N + (n0 + tx * 8));
            dst[0] = make_float4(v[0], v[1], v[2], v[3]);
            dst[1] = make_float4(v[4], v[5], v[6], v[7]);
        }
    }
}

// ---------------------------------------------------------------------------
// Sequential attractor scan over d-interleaved Wa4 (r15 structure).
// One block per batch, 128 threads (2 waves), thread e = output coord.
// r16 change: prefetch is UNCONDITIONAL via clamped quarter index — r15's
// `if (pf < nq)` put the loads in conditional blocks, forcing conservative
// (up to vmcnt(0)) waits at the join and serializing every quarter into
// issue->drain->chain (~3670 cyc/step measured). Clamped prefetches load
// valid memory (last quarter) into buffers that are never consumed
// (consumption would be at quarter pf >= nq, past loop end) — values
// bit-identical, straight-line loads, precise vmcnt(24).
// Quarter-grain pipeline distance 3 (4 x 8 float4 = 128 VGPRs, r13-proven);
// ping-pong et, ONE barrier/step (r14-proven).
// Chain is op-for-op the verified sequence: ONE accumulator, strictly
// ascending d (q asc, dq asc, x,y,z,w = d..d+3), non-fused
// __fmul_rn/__fadd_rn — bitwise contract.
// ---------------------------------------------------------------------------
__global__ __launch_bounds__(128, 1) void scan_kernel(const float* __restrict__ Wa,
                                                      const float* __restrict__ e0,
                                                      float* __restrict__ et_state,
                                                      float* __restrict__ out,
                                                      int i0, int CH) {
    const int b = blockIdx.x;
    const int e = threadIdx.x;  // 0..127

    __shared__ float et[2][128];

    int s = 0;
    if (i0 == 0) {
        const float v = e0[e];
        et[0][e] = v;
        out[(size_t)b * SS * ENC + e] = v;
    } else {
        et[0][e] = et_state[b * 128 + e];
    }
    __syncthreads();

    const int start = (i0 == 0) ? 1 : 0;
    const float4* Wb4 = (const float4*)(Wa + (size_t)b * CH * (ENC * ENC));
    const int nq = (CH - start) * 4;   // total quarter-tiles this launch
    // step stride in float4 units: ENC*ENC/4 = 4096; quarter stride: 8*128=1024

    float4 w4[4][8];   // 4 quarter buffers x 8 float4 = 128 VGPRs

    // preload quarters 0,1,2 of step `start`
    {
        const float4* S4 = Wb4 + (size_t)start * 4096 + e;
#pragma unroll
        for (int u = 0; u < 8; ++u) w4[0][u] = S4[u * 128];
#pragma unroll
        for (int u = 0; u < 8; ++u) w4[1][u] = S4[(8 + u) * 128];
#pragma unroll
        for (int u = 0; u < 8; ++u) w4[2][u] = S4[(16 + u) * 128];
    }
    asm volatile("" ::: "memory");  // loads pinned before first chain

    for (int ii = start; ii < CH; ++ii) {
        float sum = 0.f;   // ONE accumulator, ascending d across all quarters
#pragma unroll
        for (int q = 0; q < 4; ++q) {
            // UNCONDITIONAL prefetch for quarter pf (clamped): straight-line
            // loads -> precise vmcnt. Clamped (pf>=nq) loads land in buffers
            // never consumed.
            const int pf = (ii - start) * 4 + q + 3;
            const int pfc = (pf < nq) ? pf : (nq - 1);   // uniform select, no branch
            const float4* P4 = Wb4 + (size_t)(start + (pfc >> 2)) * 4096
                                   + (size_t)(pfc & 3) * 1024 + e;
#pragma unroll
            for (int u = 0; u < 8; ++u) w4[(q + 3) & 3][u] = P4[u * 128];
            asm volatile("" ::: "memory");
            // consume quarter q: d = 32q .. 32q+31, strictly ascending
#pragma unroll
            for (int dq = 0; dq < 8; ++dq) {
                const float4 t4 = *(const float4*)&et[s][q * 32 + dq * 4];
                const float4 wv = w4[q][dq];   // W[d..d+3][e], d = 32q+4dq
                sum = __fadd_rn(sum, __fmul_rn(t4.x, wv.x));
                sum = __fadd_rn(sum, __fmul_rn(t4.y, wv.y));
                sum = __fadd_rn(sum, __fmul_rn(t4.z, wv.z));
                sum = __fadd_rn(sum, __fmul_rn(t4.w, wv.w));
            }
        }
        const float v = fminf(fmaxf(sum, -5.f), 5.f);  // jnp.clip
        out[((size_t)b * SS + (i0 + ii)) * ENC + e] = v;
        et[s ^ 1][e] = v;   // this step's readers use et[s] — no conflict
        __syncthreads();    // publishes et[s^1]; orders next step's overwrite
        s ^= 1;
    }
    et_state[b * 128 + e] = et[s][e];
}

// ---------------------------------------------------------------------------
extern "C" void kernel_launch(void* const* d_in, const int* in_sizes, int n_in,
                              void* d_out, int out_size, void* d_ws, size_t ws_size,
                              hipStream_t stream) {
    const float* A  = (const float*)d_in[0];  // (B,S,E)   = (8,512,128) fp32
    const float* W1 = (const float*)d_in[1];  // (H,E)     = (512,128)  fp32
    const float* b1 = (const float*)d_in[2];  // (H,)      fp32
    const float* W2 = (const float*)d_in[3];  // (ENC*ENC,H) = (16384,512) fp32
    const float* b2 = (const float*)d_in[4];  // (ENC*ENC,) fp32
    const float* e0 = (const float*)d_in[5];  // (1,ENC)   fp32
    float* out = (float*)d_out;               // (B,S,ENC) fp32

    // Pick the largest chunk CH (steps) whose fp32 workspace fits ws_size.
    // ws layout: [et_state 4KB][hidden_c Mc*512 f32][Wa4_c Mc*16384 f32], Mc=8*CH
    int CH = 16;  // minimum (Mc=128, one M-tile); needs ~8.7 MB
    for (int c = 512; c >= 16; c >>= 1) {
        const size_t Mc = (size_t)BB * c;
        const size_t need = 4096 + Mc * HH * sizeof(float) +
                            Mc * (size_t)(ENC * ENC) * sizeof(float);
        if (need <= ws_size) { CH = c; break; }
    }
    const int Mc = BB * CH;
    int chsh = 0;
    while ((1 << chsh) < CH) ++chsh;
    const int chm1 = CH - 1;

    float* et_state = (float*)d_ws;
    float* hidden   = (float*)((char*)d_ws + 4096);
    float* Wa       = hidden + (size_t)Mc * HH;   // d-interleaved layout (Wa4)

    for (int i0 = 0; i0 < SS; i0 += CH) {
        // GEMM1: hidden_c = tanh(A[chunk rows] @ W1^T + b1)  [Mc x 512, K=128]
        dim3 g1(HH / 128, Mc / 128);
        gemm_nt<1, 1, 0><<<g1, 256, 0, stream>>>(A, W1, b1, hidden, HH, EE,
                                                 chm1, chsh, i0);
        // GEMM2: Wa4_c = (hidden_c @ W2^T + b2) stored d-interleaved
        dim3 g2((ENC * ENC) / 128, Mc / 128);
        gemm_nt<0, 0, 1><<<g2, 256, 0, stream>>>(hidden, W2, b2, Wa, ENC * ENC,
                                                 HH, 0, 0, 0);
        // scan this chunk (one workgroup per batch; fp32 state in ws)
        scan_kernel<<<BB, 128, 0, stream>>>(Wa, e0, et_state, out, i0, CH);
    }
}